// Round 1
// 942.363 us; speedup vs baseline: 1.1408x; 1.1408x over previous
//
#include <hip/hip_runtime.h>

typedef __bf16 bf16_t;
typedef bf16_t bf16x8 __attribute__((ext_vector_type(8)));
typedef bf16_t bf16x4 __attribute__((ext_vector_type(4)));
typedef float  f32x4  __attribute__((ext_vector_type(4)));

typedef const __attribute__((address_space(1))) void* gptr_t;
typedef __attribute__((address_space(3))) void* sptr_t;

#define BATCH 8
#define SEQL  4096
#define DIM   1024
#define MROWS 32768

__device__ __forceinline__ float sigmoidf_(float v) {
    return 1.0f / (1.0f + __expf(-v));
}

// ---------------- transpose + cast fp32 (K,N) -> bf16 (N,K) ----------------
// PERM=1: permute output row n so GEMM3 tiles hold (ig,fg) pairs:
//   n<1024 (ig col d): dest = (d>>6)*128 + (d&63)
//   n>=1024 (fg col d): dest = (d>>6)*128 + 64 + (d&63)
template <int PERM>
__global__ void transpose_cast(const float* __restrict__ W, bf16_t* __restrict__ WT,
                               int K, int N) {
    __shared__ float s[32][33];
    int tx = threadIdx.x, ty = threadIdx.y;
    int x = blockIdx.x * 32 + tx;   // N index
    int y = blockIdx.y * 32 + ty;   // K index
    s[ty][tx] = W[(size_t)y * N + x];
    __syncthreads();
    int n = blockIdx.x * 32 + ty;
    int k = blockIdx.y * 32 + tx;
    int nd = n;
    if (PERM) {
        if (n < 1024) nd = ((n >> 6) << 7) + (n & 63);
        else          nd = (((n - 1024) >> 6) << 7) + 64 + ((n - 1024) & 63);
    }
    WT[(size_t)nd * K + k] = (bf16_t)s[tx][ty];
}

// ---------------- scan phase 1: per-chunk sums (full D per block) ----------
__global__ void scan_chunks(const float* __restrict__ x, float* __restrict__ cs) {
    int tid = threadIdx.x;
    int b = blockIdx.x >> 6, c = blockIdx.x & 63;
    const f32x4* x4 = (const f32x4*)x;
    size_t base = ((size_t)b * SEQL + (size_t)c * 64) * 256 + tid;
    f32x4 s0 = {0.f, 0.f, 0.f, 0.f}, s1 = {0.f, 0.f, 0.f, 0.f};
#pragma unroll 8
    for (int j = 0; j < 64; j += 2) {
        s0 += x4[base + (size_t)j * 256];
        s1 += x4[base + (size_t)(j + 1) * 256];
    }
    ((f32x4*)cs)[((size_t)(b << 6) + c) * 256 + tid] = s0 + s1;
}

// ---------------- scan phase 2: exclusive prefix over 64 chunks -------------
__global__ void scan_prefix(float* __restrict__ cs) {
    int t = blockIdx.x * 256 + threadIdx.x;   // 8192 threads
    int b = t >> 10, d = t & 1023;
    size_t base = (size_t)(b << 6) * 1024 + d;
    float v[64];
#pragma unroll
    for (int c = 0; c < 64; ++c) v[c] = cs[base + (size_t)c * 1024];
    float run = 0.f;
#pragma unroll
    for (int c = 0; c < 64; ++c) {
        float tv = v[c];
        cs[base + (size_t)c * 1024] = run;
        run += tv;
    }
}

// ---------------- scan phase 3 fused: avg + LayerNorm(bf16 h) + x cast ------
__global__ __launch_bounds__(256) void scan_ln(
    const float* __restrict__ x, const float* __restrict__ cs,
    const float* __restrict__ g, const float* __restrict__ bb,
    float* __restrict__ avg, bf16_t* __restrict__ hb, bf16_t* __restrict__ xb) {
    int tid = threadIdx.x;
    int wave = tid >> 6, lane = tid & 63;
    int b = blockIdx.x >> 6, c = blockIdx.x & 63;
    __shared__ float red[8];
    const f32x4* x4 = (const f32x4*)x;
    f32x4* avg4 = (f32x4*)avg;
    bf16x4* hb4 = (bf16x4*)hb;
    bf16x4* xb4 = (bf16x4*)xb;
    f32x4 run = ((const f32x4*)cs)[((size_t)(b << 6) + c) * 256 + tid];
    f32x4 gv = ((const f32x4*)g)[tid];
    f32x4 bv = ((const f32x4*)bb)[tid];
    size_t row0 = (size_t)b * SEQL + (size_t)c * 64;
    f32x4 xv = x4[row0 * 256 + tid];
    for (int j = 0; j < 64; ++j) {
        size_t ridx = (row0 + j) * 256 + tid;
        f32x4 xnext = {0.f, 0.f, 0.f, 0.f};
        if (j < 63) xnext = x4[ridx + 256];           // prefetch next row
        run += xv;
        float inv = 1.0f / (float)(c * 64 + j + 1);
        f32x4 av = run * inv;
        avg4[ridx] = av;
        bf16x4 xo = { (bf16_t)xv[0], (bf16_t)xv[1], (bf16_t)xv[2], (bf16_t)xv[3] };
        xb4[ridx] = xo;
        float s  = av[0] + av[1] + av[2] + av[3];
        float sq = av[0]*av[0] + av[1]*av[1] + av[2]*av[2] + av[3]*av[3];
#pragma unroll
        for (int off = 32; off; off >>= 1) {
            s  += __shfl_xor(s, off);
            sq += __shfl_xor(sq, off);
        }
        if (lane == 0) { red[wave] = s; red[4 + wave] = sq; }
        __syncthreads();
        s  = red[0] + red[1] + red[2] + red[3];
        sq = red[4] + red[5] + red[6] + red[7];
        float mu  = s * (1.f / DIM);
        float var = sq * (1.f / DIM) - mu * mu;
        var = var < 0.f ? 0.f : var;
        float rs = 1.0f / sqrtf(var + 1e-6f);
        f32x4 hn = (av - mu) * rs * gv + bv;
        bf16x4 ho = { (bf16_t)hn[0], (bf16_t)hn[1], (bf16_t)hn[2], (bf16_t)hn[3] };
        hb4[ridx] = ho;
        __syncthreads();   // red[] reused next iteration
        xv = xnext;
    }
}

// ---------------- MFMA bf16 GEMM, 256x256 tile, BK=64, 8 waves --------------
// Counted-vmcnt double-buffered pipeline (T3+T4): stage tile t+1 right after
// the entry barrier, then wait vmcnt(8) = only tile t's loads (issued one full
// K-tile earlier). Raw s_barrier (no vmcnt(0) drain in the main loop).
// LDS per buffer: A[256][64] + B[256][64] bf16 (64 KiB); 2 buffers = 128 KiB.
// Swizzle: LDS position (row, ch) holds global 16B-chunk (ch ^ (row&7)).
// C = A @ Bt^T ; A row stride = kSplit; A source switches at k=kSplit.
// EPI 1: outb = bf16(relu(acc + bias[n]))
// EPI 2: v = acc + bias[n] + addsrc; outf = v; outb = bf16(v)
// EPI 4: fused gating; N-cols permuted (see transpose_cast<1>):
//        wave wn&64 -> fg col 1024+T*64+dc, else ig col T*64+dc, T=(n0+wn)>>7.
//        out[row,d] = sig(ig)*xsrc + sig(fg)*addsrc, exchanged via LDS.
template <int EPI>
__global__ __launch_bounds__(512, 2) void gemm_bt(
    const bf16_t* __restrict__ A0, const bf16_t* __restrict__ A1, int kSplit,
    const bf16_t* __restrict__ Bt, int N, int K,
    const float* __restrict__ bias, const float* __restrict__ addsrc,
    const float* __restrict__ xsrc,
    float* __restrict__ outf, bf16_t* __restrict__ outb) {
    __shared__ char smem[131072];
    const int tid = threadIdx.x;
    const int wave = tid >> 6, lane = tid & 63;

    // XCD-aware bijective swizzle (all our grids are %8 == 0)
    const int nwg = gridDim.x;
    const int q8 = nwg >> 3;
    const int lid = (blockIdx.x & 7) * q8 + ((int)blockIdx.x >> 3);
    const int nBlocks = N >> 8;
    const int m0 = (lid / nBlocks) << 8;
    const int n0 = (lid % nBlocks) << 8;

    const int wm = (wave >> 2) << 7;   // 0 / 128
    const int wn = (wave & 3) << 6;    // 0 / 64 / 128 / 192
    const int lrow16 = lane & 15;
    // swizzled k-offsets (elements) for the two kk steps; row&7 == lane&7
    const int ksw0 = ((((lane >> 4) + 0) ^ (lane & 7)) << 3);
    const int ksw1 = ((((lane >> 4) + 4) ^ (lane & 7)) << 3);

    f32x4 acc[8][4] = {};

    const int nT = K >> 6;

    auto STAGE = [&](int k0, int buf) {
        const bf16_t* Asrc;
        int ak0;
        if (k0 < kSplit) { Asrc = A0; ak0 = k0; }
        else             { Asrc = A1; ak0 = k0 - kSplit; }
        bf16_t* As = (bf16_t*)(smem + buf * 65536);
        bf16_t* Bs = As + 256 * 64;
#pragma unroll
        for (int rd = 0; rd < 4; ++rd) {
            int ci = tid + (rd << 9);
            int row = ci >> 3, ch = ci & 7;
            int chs = ch ^ (row & 7);
            const bf16_t* gp = Asrc + (size_t)(m0 + row) * kSplit + ak0 + (chs << 3);
            bf16_t* sb = As + (size_t)(ci & ~63) * 8;
            __builtin_amdgcn_global_load_lds((gptr_t)gp, (sptr_t)sb, 16, 0, 0);
        }
#pragma unroll
        for (int rd = 0; rd < 4; ++rd) {
            int ci = tid + (rd << 9);
            int row = ci >> 3, ch = ci & 7;
            int chs = ch ^ (row & 7);
            const bf16_t* gp = Bt + (size_t)(n0 + row) * K + k0 + (chs << 3);
            bf16_t* sb = Bs + (size_t)(ci & ~63) * 8;
            __builtin_amdgcn_global_load_lds((gptr_t)gp, (sptr_t)sb, 16, 0, 0);
        }
    };

    STAGE(0, 0);

    for (int t = 0; t < nT; ++t) {
        const int p = t & 1;
        __builtin_amdgcn_s_barrier();            // prev tile fully consumed
        if (t + 1 < nT) {
            STAGE((t + 1) << 6, p ^ 1);
            // wait only on tile t's 8 loads; tile t+1's 8 stay in flight
            asm volatile("s_waitcnt vmcnt(8)" ::: "memory");
        } else {
            asm volatile("s_waitcnt vmcnt(0)" ::: "memory");
        }
        __builtin_amdgcn_s_barrier();            // landed for ALL waves
        __builtin_amdgcn_sched_barrier(0);
        const bf16_t* As = (const bf16_t*)(smem + p * 65536);
        const bf16_t* Bs = As + 256 * 64;
        bf16x8 bfv[4];
#pragma unroll
        for (int ph = 0; ph < 4; ++ph) {
            const int kk = ph >> 1, mh = ph & 1;
            const int ksw = kk ? ksw1 : ksw0;
            if (mh == 0) {
#pragma unroll
                for (int ni = 0; ni < 4; ++ni)
                    bfv[ni] = *(const bf16x8*)&Bs[(wn + ni * 16 + lrow16) * 64 + ksw];
            }
            bf16x8 af[4];
#pragma unroll
            for (int mi = 0; mi < 4; ++mi)
                af[mi] = *(const bf16x8*)&As[(wm + (mh * 4 + mi) * 16 + lrow16) * 64 + ksw];
            __builtin_amdgcn_s_setprio(1);
#pragma unroll
            for (int mi = 0; mi < 4; ++mi)
#pragma unroll
                for (int ni = 0; ni < 4; ++ni)
                    acc[mh * 4 + mi][ni] = __builtin_amdgcn_mfma_f32_16x16x32_bf16(
                        af[mi], bfv[ni], acc[mh * 4 + mi][ni], 0, 0, 0);
            __builtin_amdgcn_s_setprio(0);
        }
    }

    const int erow = (lane >> 4) << 2;

    if (EPI == 4) {
        __syncthreads();                    // all waves done with As/Bs
        float* xch = (float*)smem;          // [4][128][64] exchange buffer
        const int T = (n0 + wn) >> 7;
        const int pairOff = ((((wave >> 2) << 1) | ((wave >> 1) & 1))) << 13;  // *8192
        if (wn & 64) {                      // fg waves
#pragma unroll
            for (int mi = 0; mi < 8; ++mi) {
#pragma unroll
                for (int ni = 0; ni < 4; ++ni) {
                    int dc = ni * 16 + lrow16;            // 0..63
                    float bcol = bias[1024 + T * 64 + dc];
                    int d = T * 64 + dc;
#pragma unroll
                    for (int r = 0; r < 4; ++r) {
                        int rowW = mi * 16 + erow + r;    // 0..127
                        int row = m0 + wm + rowW;
                        float v = acc[mi][ni][r] + bcol;
                        int sw = ((rowW >> 2) & 1) << 4;  // bank de-conflict
                        xch[pairOff + rowW * 64 + (dc ^ sw)] =
                            sigmoidf_(v) * addsrc[(size_t)row * 1024 + d];
                    }
                }
            }
        }
        __syncthreads();
        if (!(wn & 64)) {                   // ig waves
#pragma unroll
            for (int mi = 0; mi < 8; ++mi) {
#pragma unroll
                for (int ni = 0; ni < 4; ++ni) {
                    int dc = ni * 16 + lrow16;            // 0..63
                    float bcol = bias[T * 64 + dc];
                    int d = T * 64 + dc;
#pragma unroll
                    for (int r = 0; r < 4; ++r) {
                        int rowW = mi * 16 + erow + r;
                        int row = m0 + wm + rowW;
                        float v = acc[mi][ni][r] + bcol;
                        int sw = ((rowW >> 2) & 1) << 4;
                        float tot = sigmoidf_(v) * xsrc[(size_t)row * 1024 + d]
                                  + xch[pairOff + rowW * 64 + (dc ^ sw)];
                        outf[(size_t)row * 1024 + d] = tot;
                    }
                }
            }
        }
        return;
    }

#pragma unroll
    for (int mi = 0; mi < 8; ++mi) {
#pragma unroll
        for (int ni = 0; ni < 4; ++ni) {
            int col = n0 + wn + ni * 16 + lrow16;
            float bcol = bias[col];
#pragma unroll
            for (int r = 0; r < 4; ++r) {
                int row = m0 + wm + mi * 16 + erow + r;
                size_t idx = (size_t)row * N + col;
                float v = acc[mi][ni][r];
                if (EPI == 1) {
                    v += bcol;
                    v = v > 0.f ? v : 0.f;
                    outb[idx] = (bf16_t)v;
                } else {  // EPI == 2
                    v += bcol + addsrc[idx];
                    outf[idx] = v;
                    outb[idx] = (bf16_t)v;
                }
            }
        }
    }
}

// ---------------- launch ----------------
extern "C" void kernel_launch(void* const* d_in, const int* in_sizes, int n_in,
                              void* d_out, int out_size, void* d_ws, size_t ws_size,
                              hipStream_t stream) {
    const float* inp  = (const float*)d_in[0];
    const float* w1   = (const float*)d_in[1];
    const float* b1   = (const float*)d_in[2];
    const float* w2   = (const float*)d_in[3];
    const float* b2   = (const float*)d_in[4];
    const float* ln_g = (const float*)d_in[5];
    const float* ln_b = (const float*)d_in[6];
    const float* wg   = (const float*)d_in[7];
    const float* bg   = (const float*)d_in[8];
    float* out = (float*)d_out;

    char* w = (char*)d_ws;
    float*  avg    = (float*)w;   w += (size_t)MROWS * DIM * 4;       // 128 MB
    float*  avgout = (float*)w;   w += (size_t)MROWS * DIM * 4;       // 128 MB
    bf16_t* xb     = (bf16_t*)w;  w += (size_t)MROWS * DIM * 2;       // 64 MB
    bf16_t* hb     = (bf16_t*)w;  w += (size_t)MROWS * DIM * 2;       // 64 MB
    bf16_t* interb = (bf16_t*)w;  w += (size_t)MROWS * DIM * 2;       // 64 MB
    bf16_t* w1t    = (bf16_t*)w;  w += (size_t)DIM * DIM * 2;         // 2 MB
    bf16_t* w2t    = (bf16_t*)w;  w += (size_t)DIM * DIM * 2;         // 2 MB
    bf16_t* wgt    = (bf16_t*)w;  w += (size_t)2 * DIM * 2 * DIM * 2; // 8 MB
    float*  csum   = (float*)w;   w += (size_t)BATCH * 64 * DIM * 4;  // 2 MB
    bf16_t* aob    = hb;            // alias: h dead after GEMM1

    // weight transposes (fp32 KxN -> bf16 NxK); wg gets the ig/fg interleave
    transpose_cast<0><<<dim3(32, 32), dim3(32, 32), 0, stream>>>(w1, w1t, DIM, DIM);
    transpose_cast<0><<<dim3(32, 32), dim3(32, 32), 0, stream>>>(w2, w2t, DIM, DIM);
    transpose_cast<1><<<dim3(64, 64), dim3(32, 32), 0, stream>>>(wg, wgt, 2 * DIM, 2 * DIM);

    // prefix-mean scan + fused LN/cast
    scan_chunks<<<BATCH * 64, 256, 0, stream>>>(inp, csum);
    scan_prefix<<<32, 256, 0, stream>>>(csum);
    scan_ln<<<BATCH * 64, 256, 0, stream>>>(inp, csum, ln_g, ln_b, avg, hb, xb);

    // GEMM1: inter = relu(h @ w1 + b1)
    gemm_bt<1><<<(MROWS / 256) * (DIM / 256), 512, 0, stream>>>(
        hb, hb, DIM, w1t, DIM, DIM, b1, nullptr, nullptr, nullptr, interb);

    // GEMM2: avg_out = inter @ w2 + b2 + avg  (fp32 + bf16 stores)
    gemm_bt<2><<<(MROWS / 256) * (DIM / 256), 512, 0, stream>>>(
        interb, interb, DIM, w2t, DIM, DIM, b2, avg, nullptr, avgout, aob);

    // GEMM3 + gating fused: out = sig(ig)*x + sig(fg)*avg_out
    gemm_bt<4><<<(MROWS / 256) * (2 * DIM / 256), 512, 0, stream>>>(
        xb, aob, DIM, wgt, 2 * DIM, 2 * DIM, bg, avgout, inp, out, nullptr);
}

// Round 2
// 878.594 us; speedup vs baseline: 1.2236x; 1.0726x over previous
//
#include <hip/hip_runtime.h>

typedef __bf16 bf16_t;
typedef bf16_t bf16x8 __attribute__((ext_vector_type(8)));
typedef bf16_t bf16x4 __attribute__((ext_vector_type(4)));
typedef float  f32x4  __attribute__((ext_vector_type(4)));

typedef const __attribute__((address_space(1))) void* gptr_t;
typedef __attribute__((address_space(3))) void* sptr_t;

#define BATCH 8
#define SEQL  4096
#define DIM   1024
#define MROWS 32768

__device__ __forceinline__ float sigmoidf_(float v) {
    return 1.0f / (1.0f + __expf(-v));
}

// ---------------- transpose + cast fp32 (K,N) -> bf16 (N,K) ----------------
// PERM=1: permute output row n so GEMM3 tiles hold (ig,fg) pairs:
//   n<1024 (ig col d): dest = (d>>6)*128 + (d&63)
//   n>=1024 (fg col d): dest = (d>>6)*128 + 64 + (d&63)
template <int PERM>
__global__ void transpose_cast(const float* __restrict__ W, bf16_t* __restrict__ WT,
                               int K, int N) {
    __shared__ float s[32][33];
    int tx = threadIdx.x, ty = threadIdx.y;
    int x = blockIdx.x * 32 + tx;   // N index
    int y = blockIdx.y * 32 + ty;   // K index
    s[ty][tx] = W[(size_t)y * N + x];
    __syncthreads();
    int n = blockIdx.x * 32 + ty;
    int k = blockIdx.y * 32 + tx;
    int nd = n;
    if (PERM) {
        if (n < 1024) nd = ((n >> 6) << 7) + (n & 63);
        else          nd = (((n - 1024) >> 6) << 7) + 64 + ((n - 1024) & 63);
    }
    WT[(size_t)nd * K + k] = (bf16_t)s[tx][ty];
}

// ---------------- scan phase 1: per-chunk sums (full D per block) ----------
__global__ void scan_chunks(const float* __restrict__ x, float* __restrict__ cs) {
    int tid = threadIdx.x;
    int b = blockIdx.x >> 6, c = blockIdx.x & 63;
    const f32x4* x4 = (const f32x4*)x;
    size_t base = ((size_t)b * SEQL + (size_t)c * 64) * 256 + tid;
    f32x4 s0 = {0.f, 0.f, 0.f, 0.f}, s1 = {0.f, 0.f, 0.f, 0.f};
#pragma unroll 8
    for (int j = 0; j < 64; j += 2) {
        s0 += x4[base + (size_t)j * 256];
        s1 += x4[base + (size_t)(j + 1) * 256];
    }
    ((f32x4*)cs)[((size_t)(b << 6) + c) * 256 + tid] = s0 + s1;
}

// ---------------- scan phase 2: exclusive prefix over 64 chunks -------------
__global__ void scan_prefix(float* __restrict__ cs) {
    int t = blockIdx.x * 256 + threadIdx.x;   // 8192 threads
    int b = t >> 10, d = t & 1023;
    size_t base = (size_t)(b << 6) * 1024 + d;
    float v[64];
#pragma unroll
    for (int c = 0; c < 64; ++c) v[c] = cs[base + (size_t)c * 1024];
    float run = 0.f;
#pragma unroll
    for (int c = 0; c < 64; ++c) {
        float tv = v[c];
        cs[base + (size_t)c * 1024] = run;
        run += tv;
    }
}

// ---------------- scan phase 3 fused: avg + LayerNorm(bf16 h) + x cast ------
__global__ __launch_bounds__(256) void scan_ln(
    const float* __restrict__ x, const float* __restrict__ cs,
    const float* __restrict__ g, const float* __restrict__ bb,
    float* __restrict__ avg, bf16_t* __restrict__ hb, bf16_t* __restrict__ xb) {
    int tid = threadIdx.x;
    int wave = tid >> 6, lane = tid & 63;
    int b = blockIdx.x >> 6, c = blockIdx.x & 63;
    __shared__ float red[8];
    const f32x4* x4 = (const f32x4*)x;
    f32x4* avg4 = (f32x4*)avg;
    bf16x4* hb4 = (bf16x4*)hb;
    bf16x4* xb4 = (bf16x4*)xb;
    f32x4 run = ((const f32x4*)cs)[((size_t)(b << 6) + c) * 256 + tid];
    f32x4 gv = ((const f32x4*)g)[tid];
    f32x4 bv = ((const f32x4*)bb)[tid];
    size_t row0 = (size_t)b * SEQL + (size_t)c * 64;
    f32x4 xv = x4[row0 * 256 + tid];
    for (int j = 0; j < 64; ++j) {
        size_t ridx = (row0 + j) * 256 + tid;
        f32x4 xnext = {0.f, 0.f, 0.f, 0.f};
        if (j < 63) xnext = x4[ridx + 256];           // prefetch next row
        run += xv;
        float inv = 1.0f / (float)(c * 64 + j + 1);
        f32x4 av = run * inv;
        avg4[ridx] = av;
        bf16x4 xo = { (bf16_t)xv[0], (bf16_t)xv[1], (bf16_t)xv[2], (bf16_t)xv[3] };
        xb4[ridx] = xo;
        float s  = av[0] + av[1] + av[2] + av[3];
        float sq = av[0]*av[0] + av[1]*av[1] + av[2]*av[2] + av[3]*av[3];
#pragma unroll
        for (int off = 32; off; off >>= 1) {
            s  += __shfl_xor(s, off);
            sq += __shfl_xor(sq, off);
        }
        if (lane == 0) { red[wave] = s; red[4 + wave] = sq; }
        __syncthreads();
        s  = red[0] + red[1] + red[2] + red[3];
        sq = red[4] + red[5] + red[6] + red[7];
        float mu  = s * (1.f / DIM);
        float var = sq * (1.f / DIM) - mu * mu;
        var = var < 0.f ? 0.f : var;
        float rs = 1.0f / sqrtf(var + 1e-6f);
        f32x4 hn = (av - mu) * rs * gv + bv;
        bf16x4 ho = { (bf16_t)hn[0], (bf16_t)hn[1], (bf16_t)hn[2], (bf16_t)hn[3] };
        hb4[ridx] = ho;
        __syncthreads();   // red[] reused next iteration
        xv = xnext;
    }
}

// ---------------- MFMA bf16 GEMM, 256x256 tile, BK=64, 8 waves --------------
// 8-phase schedule (T3+T4+T5), 2 K-tiles per iteration (buf0 phases 1-4,
// buf1 phases 5-8). Each phase: stage 1 half-tile (2 global_load_lds) ->
// [vmcnt(6) on P1/P3/P5/P7] -> s_barrier -> ds_read frags -> 16 MFMA in
// setprio(1) -> s_barrier. Half-tile death schedule (steady state, tile t=2i):
//   P1: Bh0(t+1)  P2: Bh1(t+1)  P3: Amh0(t+2)  P4: Amh1(t+1)
//   P5: Bh0(t+2)  P6: Bh1(t+2)  P7: Amh0(t+3)  P8: Amh1(t+2)
// A-halves: mh0 = rd{0,2} (rows 0-63,128-191), mh1 = rd{1,3}. Every half has
// >=3 phases in flight; vmcnt(6) spares the newest 3 halves. Staging runs 2
// tiles past K (reads land in adjacent workspace arrays; writes only touch
// dead LDS regions). LDS: 2 x (A[256][64] + B[256][64]) bf16 = 128 KiB,
// chunk-XOR swizzled (proven 0 bank conflicts).
// C = A @ Bt^T ; A row stride = kSplit; A source switches at k=kSplit.
// EPI 1: outb = bf16(relu(acc + bias[n]))
// EPI 2: v = acc + bias[n] + addsrc; outf = v; outb = bf16(v)
// EPI 4: fused gating; N-cols permuted (see transpose_cast<1>).
template <int EPI>
__global__ __launch_bounds__(512, 2) void gemm_bt(
    const bf16_t* __restrict__ A0, const bf16_t* __restrict__ A1, int kSplit,
    const bf16_t* __restrict__ Bt, int N, int K,
    const float* __restrict__ bias, const float* __restrict__ addsrc,
    const float* __restrict__ xsrc,
    float* __restrict__ outf, bf16_t* __restrict__ outb) {
    __shared__ char smem[131072];
    const int tid = threadIdx.x;
    const int wave = tid >> 6, lane = tid & 63;

    // XCD-aware bijective swizzle (all our grids are %8 == 0)
    const int nwg = gridDim.x;
    const int q8 = nwg >> 3;
    const int lid = (blockIdx.x & 7) * q8 + ((int)blockIdx.x >> 3);
    const int nBlocks = N >> 8;
    const int m0 = (lid / nBlocks) << 8;
    const int n0 = (lid % nBlocks) << 8;

    const int wm = (wave >> 2) << 7;   // 0 / 128
    const int wn = (wave & 3) << 6;    // 0 / 64 / 128 / 192
    const int lrow16 = lane & 15;
    // swizzled k-offsets (elements) for the two kk steps; row&7 == lane&7
    const int ksw0 = ((((lane >> 4) + 0) ^ (lane & 7)) << 3);
    const int ksw1 = ((((lane >> 4) + 4) ^ (lane & 7)) << 3);

    f32x4 acc[8][4] = {};

    // ---- staging helpers: one half-tile = 2 global_load_lds per thread ----
    auto stageA = [&](int kt, int buf, int mh) {   // mh0: rd{0,2}  mh1: rd{1,3}
        const int k0 = kt << 6;
        const bf16_t* Asrc; int ak0;
        if (k0 < kSplit) { Asrc = A0; ak0 = k0; }
        else             { Asrc = A1; ak0 = k0 - kSplit; }
#pragma unroll
        for (int rr = 0; rr < 2; ++rr) {
            int ci = tid + ((mh + rr * 2) << 9);
            int row = ci >> 3, ch = ci & 7;
            int chs = ch ^ (row & 7);
            const bf16_t* gp = Asrc + (size_t)(m0 + row) * kSplit + ak0 + (chs << 3);
            bf16_t* sb = (bf16_t*)(smem + (buf << 16)) + (size_t)(ci & ~63) * 8;
            __builtin_amdgcn_global_load_lds((gptr_t)gp, (sptr_t)sb, 16, 0, 0);
        }
    };
    auto stageB = [&](int kt, int buf, int half) { // half0: rd{0,1}  half1: rd{2,3}
        const int k0 = kt << 6;
#pragma unroll
        for (int rr = 0; rr < 2; ++rr) {
            int ci = tid + ((half * 2 + rr) << 9);
            int row = ci >> 3, ch = ci & 7;
            int chs = ch ^ (row & 7);
            const bf16_t* gp = Bt + (size_t)(n0 + row) * K + k0 + (chs << 3);
            bf16_t* sb = (bf16_t*)(smem + (buf << 16) + 32768) + (size_t)(ci & ~63) * 8;
            __builtin_amdgcn_global_load_lds((gptr_t)gp, (sptr_t)sb, 16, 0, 0);
        }
    };

    bf16x8 af[4], bfv0[4], bfv1[4];
    auto readsAB = [&](int buf, int mh, int ksw, bf16x8* bfv) {
        const bf16_t* As_ = (const bf16_t*)(smem + (buf << 16));
        const bf16_t* Bs_ = As_ + 16384;
#pragma unroll
        for (int ni = 0; ni < 4; ++ni)
            bfv[ni] = *(const bf16x8*)&Bs_[(wn + ni * 16 + lrow16) * 64 + ksw];
#pragma unroll
        for (int mi = 0; mi < 4; ++mi)
            af[mi] = *(const bf16x8*)&As_[(wm + (mh * 4 + mi) * 16 + lrow16) * 64 + ksw];
    };
    auto readsA = [&](int buf, int mh, int ksw) {
        const bf16_t* As_ = (const bf16_t*)(smem + (buf << 16));
#pragma unroll
        for (int mi = 0; mi < 4; ++mi)
            af[mi] = *(const bf16x8*)&As_[(wm + (mh * 4 + mi) * 16 + lrow16) * 64 + ksw];
    };
    auto mfma16 = [&](int mh, bf16x8* bfv) {
        __builtin_amdgcn_s_setprio(1);
#pragma unroll
        for (int mi = 0; mi < 4; ++mi)
#pragma unroll
            for (int ni = 0; ni < 4; ++ni)
                acc[mh * 4 + mi][ni] = __builtin_amdgcn_mfma_f32_16x16x32_bf16(
                    af[mi], bfv[ni], acc[mh * 4 + mi][ni], 0, 0, 0);
        __builtin_amdgcn_s_setprio(0);
    };

#define BAR_  __builtin_amdgcn_s_barrier()
#define SB_   __builtin_amdgcn_sched_barrier(0)
#define VMW6_ asm volatile("s_waitcnt vmcnt(6)" ::: "memory")

    // prologue: Amh0(0), Bh0(0), Bh1(0), Amh0(1), Amh1(0)  (issue order matters)
    stageA(0, 0, 0);
    stageB(0, 0, 0);
    stageB(0, 0, 1);
    stageA(1, 1, 0);
    stageA(0, 0, 1);

    const int nIter = K >> 7;   // 2 K-tiles per iteration
#pragma nounroll
    for (int i = 0; i < nIter; ++i) {
        const int t2 = i << 1;
        // ---- tile t2 (buf0) ----
        stageB(t2 + 1, 1, 0);                               // P1
        VMW6_; BAR_; SB_;
        readsAB(0, 0, ksw0, bfv0); mfma16(0, bfv0);
        SB_; BAR_; SB_;

        stageB(t2 + 1, 1, 1);                               // P2
        BAR_; SB_;
        readsAB(0, 0, ksw1, bfv1); mfma16(0, bfv1);
        SB_; BAR_; SB_;

        stageA(t2 + 2, 0, 0);                               // P3
        VMW6_; BAR_; SB_;
        readsA(0, 1, ksw0); mfma16(1, bfv0);
        SB_; BAR_; SB_;

        stageA(t2 + 1, 1, 1);                               // P4
        BAR_; SB_;
        readsA(0, 1, ksw1); mfma16(1, bfv1);
        SB_; BAR_; SB_;

        // ---- tile t2+1 (buf1) ----
        stageB(t2 + 2, 0, 0);                               // P5
        VMW6_; BAR_; SB_;
        readsAB(1, 0, ksw0, bfv0); mfma16(0, bfv0);
        SB_; BAR_; SB_;

        stageB(t2 + 2, 0, 1);                               // P6
        BAR_; SB_;
        readsAB(1, 0, ksw1, bfv1); mfma16(0, bfv1);
        SB_; BAR_; SB_;

        stageA(t2 + 3, 1, 0);                               // P7
        VMW6_; BAR_; SB_;
        readsA(1, 1, ksw0); mfma16(1, bfv0);
        SB_; BAR_; SB_;

        stageA(t2 + 2, 0, 1);                               // P8
        BAR_; SB_;
        readsA(1, 1, ksw1); mfma16(1, bfv1);
        SB_; BAR_; SB_;
    }
    asm volatile("s_waitcnt vmcnt(0)" ::: "memory");        // drain tail stages

#undef BAR_
#undef SB_
#undef VMW6_

    const int erow = (lane >> 4) << 2;

    if (EPI == 4) {
        __syncthreads();                    // all waves done with As/Bs
        float* xch = (float*)smem;          // [4][128][64] exchange buffer
        const int T = (n0 + wn) >> 7;
        const int pairOff = ((((wave >> 2) << 1) | ((wave >> 1) & 1))) << 13;  // *8192
        if (wn & 64) {                      // fg waves
#pragma unroll
            for (int mi = 0; mi < 8; ++mi) {
#pragma unroll
                for (int ni = 0; ni < 4; ++ni) {
                    int dc = ni * 16 + lrow16;            // 0..63
                    float bcol = bias[1024 + T * 64 + dc];
                    int d = T * 64 + dc;
#pragma unroll
                    for (int r = 0; r < 4; ++r) {
                        int rowW = mi * 16 + erow + r;    // 0..127
                        int row = m0 + wm + rowW;
                        float v = acc[mi][ni][r] + bcol;
                        int sw = ((rowW >> 2) & 1) << 4;  // bank de-conflict
                        xch[pairOff + rowW * 64 + (dc ^ sw)] =
                            sigmoidf_(v) * addsrc[(size_t)row * 1024 + d];
                    }
                }
            }
        }
        __syncthreads();
        if (!(wn & 64)) {                   // ig waves
#pragma unroll
            for (int mi = 0; mi < 8; ++mi) {
#pragma unroll
                for (int ni = 0; ni < 4; ++ni) {
                    int dc = ni * 16 + lrow16;            // 0..63
                    float bcol = bias[T * 64 + dc];
                    int d = T * 64 + dc;
#pragma unroll
                    for (int r = 0; r < 4; ++r) {
                        int rowW = mi * 16 + erow + r;
                        int row = m0 + wm + rowW;
                        float v = acc[mi][ni][r] + bcol;
                        int sw = ((rowW >> 2) & 1) << 4;
                        float tot = sigmoidf_(v) * xsrc[(size_t)row * 1024 + d]
                                  + xch[pairOff + rowW * 64 + (dc ^ sw)];
                        outf[(size_t)row * 1024 + d] = tot;
                    }
                }
            }
        }
        return;
    }

#pragma unroll
    for (int mi = 0; mi < 8; ++mi) {
#pragma unroll
        for (int ni = 0; ni < 4; ++ni) {
            int col = n0 + wn + ni * 16 + lrow16;
            float bcol = bias[col];
#pragma unroll
            for (int r = 0; r < 4; ++r) {
                int row = m0 + wm + mi * 16 + erow + r;
                size_t idx = (size_t)row * N + col;
                float v = acc[mi][ni][r];
                if (EPI == 1) {
                    v += bcol;
                    v = v > 0.f ? v : 0.f;
                    outb[idx] = (bf16_t)v;
                } else {  // EPI == 2
                    v += bcol + addsrc[idx];
                    outf[idx] = v;
                    outb[idx] = (bf16_t)v;
                }
            }
        }
    }
}

// ---------------- launch ----------------
extern "C" void kernel_launch(void* const* d_in, const int* in_sizes, int n_in,
                              void* d_out, int out_size, void* d_ws, size_t ws_size,
                              hipStream_t stream) {
    const float* inp  = (const float*)d_in[0];
    const float* w1   = (const float*)d_in[1];
    const float* b1   = (const float*)d_in[2];
    const float* w2   = (const float*)d_in[3];
    const float* b2   = (const float*)d_in[4];
    const float* ln_g = (const float*)d_in[5];
    const float* ln_b = (const float*)d_in[6];
    const float* wg   = (const float*)d_in[7];
    const float* bg   = (const float*)d_in[8];
    float* out = (float*)d_out;

    char* w = (char*)d_ws;
    float*  avg    = (float*)w;   w += (size_t)MROWS * DIM * 4;       // 128 MB
    float*  avgout = (float*)w;   w += (size_t)MROWS * DIM * 4;       // 128 MB
    bf16_t* xb     = (bf16_t*)w;  w += (size_t)MROWS * DIM * 2;       // 64 MB
    bf16_t* hb     = (bf16_t*)w;  w += (size_t)MROWS * DIM * 2;       // 64 MB
    bf16_t* interb = (bf16_t*)w;  w += (size_t)MROWS * DIM * 2;       // 64 MB
    bf16_t* w1t    = (bf16_t*)w;  w += (size_t)DIM * DIM * 2;         // 2 MB
    bf16_t* w2t    = (bf16_t*)w;  w += (size_t)DIM * DIM * 2;         // 2 MB
    bf16_t* wgt    = (bf16_t*)w;  w += (size_t)2 * DIM * 2 * DIM * 2; // 8 MB
    float*  csum   = (float*)w;   w += (size_t)BATCH * 64 * DIM * 4;  // 2 MB
    bf16_t* aob    = hb;            // alias: h dead after GEMM1

    // weight transposes (fp32 KxN -> bf16 NxK); wg gets the ig/fg interleave
    transpose_cast<0><<<dim3(32, 32), dim3(32, 32), 0, stream>>>(w1, w1t, DIM, DIM);
    transpose_cast<0><<<dim3(32, 32), dim3(32, 32), 0, stream>>>(w2, w2t, DIM, DIM);
    transpose_cast<1><<<dim3(64, 64), dim3(32, 32), 0, stream>>>(wg, wgt, 2 * DIM, 2 * DIM);

    // prefix-mean scan + fused LN/cast
    scan_chunks<<<BATCH * 64, 256, 0, stream>>>(inp, csum);
    scan_prefix<<<32, 256, 0, stream>>>(csum);
    scan_ln<<<BATCH * 64, 256, 0, stream>>>(inp, csum, ln_g, ln_b, avg, hb, xb);

    // GEMM1: inter = relu(h @ w1 + b1)
    gemm_bt<1><<<(MROWS / 256) * (DIM / 256), 512, 0, stream>>>(
        hb, hb, DIM, w1t, DIM, DIM, b1, nullptr, nullptr, nullptr, interb);

    // GEMM2: avg_out = inter @ w2 + b2 + avg  (fp32 + bf16 stores)
    gemm_bt<2><<<(MROWS / 256) * (DIM / 256), 512, 0, stream>>>(
        interb, interb, DIM, w2t, DIM, DIM, b2, avg, nullptr, avgout, aob);

    // GEMM3 + gating fused: out = sig(ig)*x + sig(fg)*avg_out
    gemm_bt<4><<<(MROWS / 256) * (2 * DIM / 256), 512, 0, stream>>>(
        xb, aob, DIM, wgt, 2 * DIM, 2 * DIM, bg, avgout, inp, out, nullptr);
}

// Round 3
// 873.158 us; speedup vs baseline: 1.2313x; 1.0062x over previous
//
#include <hip/hip_runtime.h>

typedef __bf16 bf16_t;
typedef bf16_t bf16x8 __attribute__((ext_vector_type(8)));
typedef bf16_t bf16x4 __attribute__((ext_vector_type(4)));
typedef float  f32x4  __attribute__((ext_vector_type(4)));

typedef const __attribute__((address_space(1))) void* gptr_t;
typedef __attribute__((address_space(3))) void* sptr_t;

#define BATCH 8
#define SEQL  4096
#define DIM   1024
#define MROWS 32768

__device__ __forceinline__ float sigmoidf_(float v) {
    return 1.0f / (1.0f + __expf(-v));
}

// ---------------- transpose + cast fp32 (K,N) -> bf16 (N,K) ----------------
// PERM=1: permute output row n so GEMM3 tiles hold (ig,fg) pairs:
//   n<1024 (ig col d): dest = (d>>6)*128 + (d&63)
//   n>=1024 (fg col d): dest = (d>>6)*128 + 64 + (d&63)
template <int PERM>
__global__ void transpose_cast(const float* __restrict__ W, bf16_t* __restrict__ WT,
                               int K, int N) {
    __shared__ float s[32][33];
    int tx = threadIdx.x, ty = threadIdx.y;
    int x = blockIdx.x * 32 + tx;   // N index
    int y = blockIdx.y * 32 + ty;   // K index
    s[ty][tx] = W[(size_t)y * N + x];
    __syncthreads();
    int n = blockIdx.x * 32 + ty;
    int k = blockIdx.y * 32 + tx;
    int nd = n;
    if (PERM) {
        if (n < 1024) nd = ((n >> 6) << 7) + (n & 63);
        else          nd = (((n - 1024) >> 6) << 7) + 64 + ((n - 1024) & 63);
    }
    WT[(size_t)nd * K + k] = (bf16_t)s[tx][ty];
}

// ---------------- scan phase 1: per-chunk sums (full D per block) ----------
__global__ void scan_chunks(const float* __restrict__ x, float* __restrict__ cs) {
    int tid = threadIdx.x;
    int b = blockIdx.x >> 6, c = blockIdx.x & 63;
    const f32x4* x4 = (const f32x4*)x;
    size_t base = ((size_t)b * SEQL + (size_t)c * 64) * 256 + tid;
    f32x4 s0 = {0.f, 0.f, 0.f, 0.f}, s1 = {0.f, 0.f, 0.f, 0.f};
#pragma unroll 8
    for (int j = 0; j < 64; j += 2) {
        s0 += x4[base + (size_t)j * 256];
        s1 += x4[base + (size_t)(j + 1) * 256];
    }
    ((f32x4*)cs)[((size_t)(b << 6) + c) * 256 + tid] = s0 + s1;
}

// ---------------- scan phase 2: exclusive prefix over 64 chunks -------------
__global__ void scan_prefix(float* __restrict__ cs) {
    int t = blockIdx.x * 256 + threadIdx.x;   // 8192 threads
    int b = t >> 10, d = t & 1023;
    size_t base = (size_t)(b << 6) * 1024 + d;
    float v[64];
#pragma unroll
    for (int c = 0; c < 64; ++c) v[c] = cs[base + (size_t)c * 1024];
    float run = 0.f;
#pragma unroll
    for (int c = 0; c < 64; ++c) {
        float tv = v[c];
        cs[base + (size_t)c * 1024] = run;
        run += tv;
    }
}

// ---------------- scan phase 3 fused: avg + LayerNorm(bf16 h) + x cast ------
__global__ __launch_bounds__(256) void scan_ln(
    const float* __restrict__ x, const float* __restrict__ cs,
    const float* __restrict__ g, const float* __restrict__ bb,
    float* __restrict__ avg, bf16_t* __restrict__ hb, bf16_t* __restrict__ xb) {
    int tid = threadIdx.x;
    int wave = tid >> 6, lane = tid & 63;
    int b = blockIdx.x >> 6, c = blockIdx.x & 63;
    __shared__ float red[8];
    const f32x4* x4 = (const f32x4*)x;
    f32x4* avg4 = (f32x4*)avg;
    bf16x4* hb4 = (bf16x4*)hb;
    bf16x4* xb4 = (bf16x4*)xb;
    f32x4 run = ((const f32x4*)cs)[((size_t)(b << 6) + c) * 256 + tid];
    f32x4 gv = ((const f32x4*)g)[tid];
    f32x4 bv = ((const f32x4*)bb)[tid];
    size_t row0 = (size_t)b * SEQL + (size_t)c * 64;
    f32x4 xv = x4[row0 * 256 + tid];
    for (int j = 0; j < 64; ++j) {
        size_t ridx = (row0 + j) * 256 + tid;
        f32x4 xnext = {0.f, 0.f, 0.f, 0.f};
        if (j < 63) xnext = x4[ridx + 256];           // prefetch next row
        run += xv;
        float inv = 1.0f / (float)(c * 64 + j + 1);
        f32x4 av = run * inv;
        avg4[ridx] = av;
        bf16x4 xo = { (bf16_t)xv[0], (bf16_t)xv[1], (bf16_t)xv[2], (bf16_t)xv[3] };
        xb4[ridx] = xo;
        float s  = av[0] + av[1] + av[2] + av[3];
        float sq = av[0]*av[0] + av[1]*av[1] + av[2]*av[2] + av[3]*av[3];
#pragma unroll
        for (int off = 32; off; off >>= 1) {
            s  += __shfl_xor(s, off);
            sq += __shfl_xor(sq, off);
        }
        if (lane == 0) { red[wave] = s; red[4 + wave] = sq; }
        __syncthreads();
        s  = red[0] + red[1] + red[2] + red[3];
        sq = red[4] + red[5] + red[6] + red[7];
        float mu  = s * (1.f / DIM);
        float var = sq * (1.f / DIM) - mu * mu;
        var = var < 0.f ? 0.f : var;
        float rs = 1.0f / sqrtf(var + 1e-6f);
        f32x4 hn = (av - mu) * rs * gv + bv;
        bf16x4 ho = { (bf16_t)hn[0], (bf16_t)hn[1], (bf16_t)hn[2], (bf16_t)hn[3] };
        hb4[ridx] = ho;
        __syncthreads();   // red[] reused next iteration
        xv = xnext;
    }
}

// ---------------- MFMA bf16 GEMM, 256x256 tile, BK=64, 8 waves --------------
// m201-style 8-phase: each window = {ds_read frags; stage 1 half (2 DMA);
// [vmcnt(6) at W4/W8]; s_barrier; lgkmcnt(0); setprio(1) 16 MFMA setprio(0);
// s_barrier}. Reads issued in the inter-barrier window hide LDS latency.
// LDS (160 KiB): A double-buffered 2x32 KiB at [0,64K); B TRIPLE-buffered
// 3x32 KiB slots at [64K,160K) (slot = tile%3) so B halves of tile t+2 can be
// staged while tile t's slot is still being read (writer slot (t+2)%3 never
// aliases readers of t, t+1).
// Window schedule (tile t0=2i in buf0, t0+1 in buf1; sl0=t0%3, sl1, sl2):
//   W1: rd A-mh0/k0 + B(sl0)/k0 | st Amh1(t0+1)->buf1
//   W2: rd A-mh0/k1 + B(sl0)/k1 | st Bh0(t0+2)->sl2
//   W3: rd A-mh1/k0             | st Amh0(t0+2)->buf0   (A-mh0 last read W2)
//   W4: rd A-mh1/k1             | st Bh1(t0+2)->sl2, vmcnt(6)
//   W5-W8: mirror for tile t0+1 (stages Amh1(t0+2), Bh0/1(t0+3)->sl0,
//          Amh0(t0+3)->buf1), vmcnt(6) at W8.
// vmcnt(6) at W4 lands Amh1(t0+1) (4th-from-last) => tile t0+1 complete for
// W5 reads; at W8 lands Amh1(t0+2) => tile t0+2 complete for next W1.
// Every stage target's previous contents were last read >=1 window earlier.
// Chunk-XOR swizzle unchanged (0 bank conflicts).
// C = A @ Bt^T ; A row stride = kSplit; A source switches at k=kSplit.
// EPI 1: outb = bf16(relu(acc + bias[n]))
// EPI 2: v = acc + bias[n] + addsrc; outf = v; outb = bf16(v)
// EPI 4: fused gating; N-cols permuted (see transpose_cast<1>).
template <int EPI>
__global__ __launch_bounds__(512, 2) void gemm_bt(
    const bf16_t* __restrict__ A0, const bf16_t* __restrict__ A1, int kSplit,
    const bf16_t* __restrict__ Bt, int N, int K,
    const float* __restrict__ bias, const float* __restrict__ addsrc,
    const float* __restrict__ xsrc,
    float* __restrict__ outf, bf16_t* __restrict__ outb) {
    __shared__ char smem[163840];
    const int tid = threadIdx.x;
    const int wave = tid >> 6, lane = tid & 63;

    // XCD-aware bijective swizzle (all our grids are %8 == 0)
    const int nwg = gridDim.x;
    const int q8 = nwg >> 3;
    const int lid = (blockIdx.x & 7) * q8 + ((int)blockIdx.x >> 3);
    const int nBlocks = N >> 8;
    const int m0 = (lid / nBlocks) << 8;
    const int n0 = (lid % nBlocks) << 8;

    const int wm = (wave >> 2) << 7;   // 0 / 128
    const int wn = (wave & 3) << 6;    // 0 / 64 / 128 / 192
    const int lrow16 = lane & 15;
    // swizzled k-offsets (elements) for the two kk steps; row&7 == lane&7
    const int ksw0 = ((((lane >> 4) + 0) ^ (lane & 7)) << 3);
    const int ksw1 = ((((lane >> 4) + 4) ^ (lane & 7)) << 3);

    f32x4 acc[8][4] = {};

    // ---- staging: one half = 2 global_load_lds per thread ----
    auto stageA = [&](int kt, int mh) {            // A half mh of tile kt -> buf kt&1
        const int k0 = kt << 6;
        const bf16_t* Asrc; int ak0;
        if (k0 < kSplit) { Asrc = A0; ak0 = k0; }
        else             { Asrc = A1; ak0 = k0 - kSplit; }
        char* base = smem + ((kt & 1) << 15);
#pragma unroll
        for (int rr = 0; rr < 2; ++rr) {
            int ci = tid + ((mh + rr * 2) << 9);
            int row = ci >> 3, ch = ci & 7;
            int chs = ch ^ (row & 7);
            const bf16_t* gp = Asrc + (size_t)(m0 + row) * kSplit + ak0 + (chs << 3);
            bf16_t* sb = (bf16_t*)base + (size_t)(ci & ~63) * 8;
            __builtin_amdgcn_global_load_lds((gptr_t)gp, (sptr_t)sb, 16, 0, 0);
        }
    };
    auto stageB = [&](int kt, int slot, int half) { // B half of tile kt -> slot
        const int k0 = kt << 6;
        char* base = smem + 65536 + (slot << 15);
#pragma unroll
        for (int rr = 0; rr < 2; ++rr) {
            int ci = tid + ((half * 2 + rr) << 9);
            int row = ci >> 3, ch = ci & 7;
            int chs = ch ^ (row & 7);
            const bf16_t* gp = Bt + (size_t)(n0 + row) * K + k0 + (chs << 3);
            bf16_t* sb = (bf16_t*)base + (size_t)(ci & ~63) * 8;
            __builtin_amdgcn_global_load_lds((gptr_t)gp, (sptr_t)sb, 16, 0, 0);
        }
    };

    bf16x8 af[4], bfv0[4], bfv1[4];
    auto readA = [&](int buf, int mh, int ksw) {
        const bf16_t* As_ = (const bf16_t*)(smem + (buf << 15));
#pragma unroll
        for (int mi = 0; mi < 4; ++mi)
            af[mi] = *(const bf16x8*)&As_[(wm + (mh * 4 + mi) * 16 + lrow16) * 64 + ksw];
    };
    auto readB = [&](int slot, int ksw, bf16x8* bfv) {
        const bf16_t* Bs_ = (const bf16_t*)(smem + 65536 + (slot << 15));
#pragma unroll
        for (int ni = 0; ni < 4; ++ni)
            bfv[ni] = *(const bf16x8*)&Bs_[(wn + ni * 16 + lrow16) * 64 + ksw];
    };
    auto mfma16 = [&](int mh, bf16x8* bfv) {
        __builtin_amdgcn_s_setprio(1);
#pragma unroll
        for (int mi = 0; mi < 4; ++mi)
#pragma unroll
            for (int ni = 0; ni < 4; ++ni)
                acc[mh * 4 + mi][ni] = __builtin_amdgcn_mfma_f32_16x16x32_bf16(
                    af[mi], bfv[ni], acc[mh * 4 + mi][ni], 0, 0, 0);
        __builtin_amdgcn_s_setprio(0);
    };

#define BAR_  __builtin_amdgcn_s_barrier()
#define SB_   __builtin_amdgcn_sched_barrier(0)
#define LG0_  asm volatile("s_waitcnt lgkmcnt(0)" ::: "memory")
#define VMW6_ asm volatile("s_waitcnt vmcnt(6)" ::: "memory")

    // prologue: tile0 (4 halves) then tile1 (3 halves; Amh1(1) staged at W1)
    stageA(0, 0);          // Amh0(0) -> buf0
    stageA(0, 1);          // Amh1(0) -> buf0
    stageB(0, 0, 0);       // Bh0(0)  -> slot0
    stageB(0, 0, 1);       // Bh1(0)  -> slot0
    stageA(1, 0);          // Amh0(1) -> buf1
    stageB(1, 1, 0);       // Bh0(1)  -> slot1
    stageB(1, 1, 1);       // Bh1(1)  -> slot1
    VMW6_;                 // 14 loads issued; first 8 (= tile0) landed
    BAR_;

    const int nIter = K >> 7;   // 2 K-tiles per iteration
    int sA = 0;                 // B slot of tile t0 = 2i
#pragma nounroll
    for (int i = 0; i < nIter; ++i) {
        const int t0 = i << 1;
        int sl1 = sA + 1; if (sl1 >= 3) sl1 -= 3;
        int sl2 = sl1 + 1; if (sl2 >= 3) sl2 -= 3;

        // ---- tile t0 (buf0, B slot sA) ----
        readA(0, 0, ksw0); readB(sA, ksw0, bfv0);           // W1
        stageA(t0 + 1, 1);
        BAR_; LG0_; SB_; mfma16(0, bfv0); BAR_;

        readA(0, 0, ksw1); readB(sA, ksw1, bfv1);           // W2
        stageB(t0 + 2, sl2, 0);
        BAR_; LG0_; SB_; mfma16(0, bfv1); BAR_;

        readA(0, 1, ksw0);                                  // W3
        stageA(t0 + 2, 0);
        BAR_; LG0_; SB_; mfma16(1, bfv0); BAR_;

        readA(0, 1, ksw1);                                  // W4
        stageB(t0 + 2, sl2, 1);
        VMW6_;
        BAR_; LG0_; SB_; mfma16(1, bfv1); BAR_;

        // ---- tile t0+1 (buf1, B slot sl1) ----
        readA(1, 0, ksw0); readB(sl1, ksw0, bfv0);          // W5
        stageA(t0 + 2, 1);
        BAR_; LG0_; SB_; mfma16(0, bfv0); BAR_;

        readA(1, 0, ksw1); readB(sl1, ksw1, bfv1);          // W6
        stageB(t0 + 3, sA, 0);
        BAR_; LG0_; SB_; mfma16(0, bfv1); BAR_;

        readA(1, 1, ksw0);                                  // W7
        stageA(t0 + 3, 0);
        BAR_; LG0_; SB_; mfma16(1, bfv0); BAR_;

        readA(1, 1, ksw1);                                  // W8
        stageB(t0 + 3, sA, 1);
        VMW6_;
        BAR_; LG0_; SB_; mfma16(1, bfv1); BAR_;

        sA += 2; if (sA >= 3) sA -= 3;
    }
    asm volatile("s_waitcnt vmcnt(0)" ::: "memory");        // drain tail stages

#undef BAR_
#undef SB_
#undef LG0_
#undef VMW6_

    const int erow = (lane >> 4) << 2;

    if (EPI == 4) {
        __syncthreads();                    // tail DMAs drained in all waves
        float* xch = (float*)smem;          // [4][128][64] exchange buffer
        const int T = (n0 + wn) >> 7;
        const int pairOff = ((((wave >> 2) << 1) | ((wave >> 1) & 1))) << 13;  // *8192
        if (wn & 64) {                      // fg waves
#pragma unroll
            for (int mi = 0; mi < 8; ++mi) {
#pragma unroll
                for (int ni = 0; ni < 4; ++ni) {
                    int dc = ni * 16 + lrow16;            // 0..63
                    float bcol = bias[1024 + T * 64 + dc];
                    int d = T * 64 + dc;
#pragma unroll
                    for (int r = 0; r < 4; ++r) {
                        int rowW = mi * 16 + erow + r;    // 0..127
                        int row = m0 + wm + rowW;
                        float v = acc[mi][ni][r] + bcol;
                        int sw = ((rowW >> 2) & 1) << 4;  // bank de-conflict
                        xch[pairOff + rowW * 64 + (dc ^ sw)] =
                            sigmoidf_(v) * addsrc[(size_t)row * 1024 + d];
                    }
                }
            }
        }
        __syncthreads();
        if (!(wn & 64)) {                   // ig waves
#pragma unroll
            for (int mi = 0; mi < 8; ++mi) {
#pragma unroll
                for (int ni = 0; ni < 4; ++ni) {
                    int dc = ni * 16 + lrow16;            // 0..63
                    float bcol = bias[T * 64 + dc];
                    int d = T * 64 + dc;
#pragma unroll
                    for (int r = 0; r < 4; ++r) {
                        int rowW = mi * 16 + erow + r;
                        int row = m0 + wm + rowW;
                        float v = acc[mi][ni][r] + bcol;
                        int sw = ((rowW >> 2) & 1) << 4;
                        float tot = sigmoidf_(v) * xsrc[(size_t)row * 1024 + d]
                                  + xch[pairOff + rowW * 64 + (dc ^ sw)];
                        outf[(size_t)row * 1024 + d] = tot;
                    }
                }
            }
        }
        return;
    }

#pragma unroll
    for (int mi = 0; mi < 8; ++mi) {
#pragma unroll
        for (int ni = 0; ni < 4; ++ni) {
            int col = n0 + wn + ni * 16 + lrow16;
            float bcol = bias[col];
#pragma unroll
            for (int r = 0; r < 4; ++r) {
                int row = m0 + wm + mi * 16 + erow + r;
                size_t idx = (size_t)row * N + col;
                float v = acc[mi][ni][r];
                if (EPI == 1) {
                    v += bcol;
                    v = v > 0.f ? v : 0.f;
                    outb[idx] = (bf16_t)v;
                } else {  // EPI == 2
                    v += bcol + addsrc[idx];
                    outf[idx] = v;
                    outb[idx] = (bf16_t)v;
                }
            }
        }
    }
}

// ---------------- launch ----------------
extern "C" void kernel_launch(void* const* d_in, const int* in_sizes, int n_in,
                              void* d_out, int out_size, void* d_ws, size_t ws_size,
                              hipStream_t stream) {
    const float* inp  = (const float*)d_in[0];
    const float* w1   = (const float*)d_in[1];
    const float* b1   = (const float*)d_in[2];
    const float* w2   = (const float*)d_in[3];
    const float* b2   = (const float*)d_in[4];
    const float* ln_g = (const float*)d_in[5];
    const float* ln_b = (const float*)d_in[6];
    const float* wg   = (const float*)d_in[7];
    const float* bg   = (const float*)d_in[8];
    float* out = (float*)d_out;

    char* w = (char*)d_ws;
    float*  avg    = (float*)w;   w += (size_t)MROWS * DIM * 4;       // 128 MB
    float*  avgout = (float*)w;   w += (size_t)MROWS * DIM * 4;       // 128 MB
    bf16_t* xb     = (bf16_t*)w;  w += (size_t)MROWS * DIM * 2;       // 64 MB
    bf16_t* hb     = (bf16_t*)w;  w += (size_t)MROWS * DIM * 2;       // 64 MB
    bf16_t* interb = (bf16_t*)w;  w += (size_t)MROWS * DIM * 2;       // 64 MB
    bf16_t* w1t    = (bf16_t*)w;  w += (size_t)DIM * DIM * 2;         // 2 MB
    bf16_t* w2t    = (bf16_t*)w;  w += (size_t)DIM * DIM * 2;         // 2 MB
    bf16_t* wgt    = (bf16_t*)w;  w += (size_t)2 * DIM * 2 * DIM * 2; // 8 MB
    float*  csum   = (float*)w;   w += (size_t)BATCH * 64 * DIM * 4;  // 2 MB
    bf16_t* aob    = hb;            // alias: h dead after GEMM1

    // weight transposes (fp32 KxN -> bf16 NxK); wg gets the ig/fg interleave
    transpose_cast<0><<<dim3(32, 32), dim3(32, 32), 0, stream>>>(w1, w1t, DIM, DIM);
    transpose_cast<0><<<dim3(32, 32), dim3(32, 32), 0, stream>>>(w2, w2t, DIM, DIM);
    transpose_cast<1><<<dim3(64, 64), dim3(32, 32), 0, stream>>>(wg, wgt, 2 * DIM, 2 * DIM);

    // prefix-mean scan + fused LN/cast
    scan_chunks<<<BATCH * 64, 256, 0, stream>>>(inp, csum);
    scan_prefix<<<32, 256, 0, stream>>>(csum);
    scan_ln<<<BATCH * 64, 256, 0, stream>>>(inp, csum, ln_g, ln_b, avg, hb, xb);

    // GEMM1: inter = relu(h @ w1 + b1)
    gemm_bt<1><<<(MROWS / 256) * (DIM / 256), 512, 0, stream>>>(
        hb, hb, DIM, w1t, DIM, DIM, b1, nullptr, nullptr, nullptr, interb);

    // GEMM2: avg_out = inter @ w2 + b2 + avg  (fp32 + bf16 stores)
    gemm_bt<2><<<(MROWS / 256) * (DIM / 256), 512, 0, stream>>>(
        interb, interb, DIM, w2t, DIM, DIM, b2, avg, nullptr, avgout, aob);

    // GEMM3 + gating fused: out = sig(ig)*x + sig(fg)*avg_out
    gemm_bt<4><<<(MROWS / 256) * (2 * DIM / 256), 512, 0, stream>>>(
        xb, aob, DIM, wgt, 2 * DIM, 2 * DIM, bg, avgout, inp, out, nullptr);
}